// Round 6
// baseline (1511.386 us; speedup 1.0000x reference)
//
#include <hip/hip_runtime.h>
#include <math.h>
#include <stdint.h>

// SLAYER 2-layer SNN. Round 6: gemm event-loop rework.
//   bitifyT -> per layer: [sparse bit-GEMM -> dense FIR conv -> sequential scan]
//   -> bits_to_f32T.
// R5 diagnosis: gemm 30% VALU / 70% stall; per-event cvt_f64 + shallow MLP.
// R6: f64 weights in LDS (cvt at staging), 32-bit masks (1 readlane/j),
// two interleaved t-streams per inner loop (2 independent add chains),
// TPW=16 variant for layer 2 (4 blocks/CU).
// All fp64 accumulation, fp32-rounded taps (absmax 0.0 rounds 1-5).

#define TT     256
#define KLEN   62          // taps 0..61
#define THETA  10.0

// ============================ bitify (transposed) ===========================
// x: [32][1024][256] f32 {0,1}; bitsT: [b][32 words][256 t]
__global__ __launch_bounds__(256)
void bitifyT(const float* __restrict__ x, uint32_t* __restrict__ bitsT)
{
    const int b  = blockIdx.x;
    const int ig = blockIdx.y;            // group of 128 inputs (4 words)
    const int t  = threadIdx.x;
    const float* xp = x     + ((size_t)b*1024 + ig*128)*TT + t;
    uint32_t*    bp = bitsT + ((size_t)b*32 + ig*4)*TT + t;
    for (int wi = 0; wi < 4; ++wi) {
        uint32_t wb = 0;
        #pragma unroll
        for (int j = 0; j < 32; ++j)
            wb |= (xp[(size_t)(wi*32 + j)*TT] >= 0.5f) ? (1u << j) : 0u;
        bp[(size_t)wi * TT] = wb;
    }
}

// ========================== sparse GEMM =====================================
// a[b][t][o] = sum over spiking i of w[o][i]   (fp64)
// block: 64 outputs x 4*TPW t (4 waves x TPW t). lane = o.
// Weights staged in LDS as f64 (32 i x 64 o, double-buffered, 33 KB).
// Spike masks: one coalesced dword load covers 64/TPW chunks of 32 i;
// per-j 32-bit masks via v_readlane. Inner loop interleaves two t-streams.
template<int I, int TPW>
__global__ __launch_bounds__(256)
void gemm_sparse(const uint32_t* __restrict__ bitsT,   // [B][I/32][TT]
                 const float*    __restrict__ w,       // slice base, stride I
                 double*         __restrict__ a_out,   // [B][TT][OS]
                 int OS)
{
    constexpr int IW  = I / 32;
    constexpr int NC  = I / 32;          // 32-i chunks
    constexpr int CPL = 64 / TPW;        // chunks per mask load
    constexpr int LSH = (TPW == 32) ? 5 : 4;
    __shared__ double wsh[2][32 * 65];   // 33.3 KB

    const int tid  = threadIdx.x;
    const int lane = tid & 63;
    const int wvu  = tid >> 6;
    const int b    = blockIdx.z;
    const int o0   = blockIdx.x * 64;
    const int t0   = blockIdx.y * (4 * TPW) + wvu * TPW;

    double acc[TPW];
    #pragma unroll
    for (int j = 0; j < TPW; ++j) acc[j] = 0.0;

    const int orow = tid >> 3;           // 0..31
    const int il4  = (tid & 7) * 4;      // 0..28

    float4 wreg[2];
    auto ldw = [&](int ic) {
        #pragma unroll
        for (int p = 0; p < 2; ++p)
            wreg[p] = *(const float4*)(w + (size_t)(o0 + orow + p*32) * I + ic*32 + il4);
    };
    auto stw = [&](int buf) {
        double* d = &wsh[buf][0];
        #pragma unroll
        for (int p = 0; p < 2; ++p) {
            const int oo = orow + p * 32;
            d[(il4 + 0) * 65 + oo] = (double)wreg[p].x;
            d[(il4 + 1) * 65 + oo] = (double)wreg[p].y;
            d[(il4 + 2) * 65 + oo] = (double)wreg[p].z;
            d[(il4 + 3) * 65 + oo] = (double)wreg[p].w;
        }
    };
    auto ldm = [&](int ic) -> uint32_t {
        return bitsT[((size_t)b * IW + (ic & ~(CPL - 1)) + (lane >> LSH)) * TT
                     + t0 + (lane & (TPW - 1))];
    };

    ldw(0);
    uint32_t mw = ldm(0);
    stw(0);
    __syncthreads();

    for (int ic = 0; ic < NC; ++ic) {
        const bool more = (ic + 1 < NC);
        uint32_t mwn = mw;
        if (more) {
            ldw(ic + 1);
            if (((ic + 1) & (CPL - 1)) == 0) mwn = ldm(ic + 1);
        }
        const double* wp = wsh[ic & 1];
        const int mbase = (ic & (CPL - 1)) * TPW;
        for (int jj = 0; jj < TPW / 2; ++jj) {
            uint32_t mA = (uint32_t)__builtin_amdgcn_readlane((int)mw, mbase + jj);
            uint32_t mB = (uint32_t)__builtin_amdgcn_readlane((int)mw, mbase + TPW/2 + jj);
            double sA0 = 0.0, sA1 = 0.0, sB0 = 0.0, sB1 = 0.0;
            while (mA | mB) {   // two independent add chains, 4 LDS reads in flight
                double fA0 = 0.0, fA1 = 0.0, fB0 = 0.0, fB1 = 0.0;
                int p;
                if (mA) { p = __builtin_ctz(mA); mA &= mA - 1; fA0 = wp[p*65 + lane]; }
                if (mA) { p = __builtin_ctz(mA); mA &= mA - 1; fA1 = wp[p*65 + lane]; }
                if (mB) { p = __builtin_ctz(mB); mB &= mB - 1; fB0 = wp[p*65 + lane]; }
                if (mB) { p = __builtin_ctz(mB); mB &= mB - 1; fB1 = wp[p*65 + lane]; }
                sA0 += fA0; sA1 += fA1; sB0 += fB0; sB1 += fB1;
            }
            acc[jj]           += sA0 + sA1;
            acc[jj + TPW/2]   += sB0 + sB1;
        }
        if (more) { stw((ic + 1) & 1); mw = mwn; }
        __syncthreads();
    }

    double* aout = a_out + ((size_t)b * TT + t0) * OS + o0 + lane;
    #pragma unroll
    for (int j = 0; j < TPW; ++j) aout[(size_t)j * OS] = acc[j];
}

// ========================== FIR conv ========================================
// u[b][t][o] = sum_{k=1..61} srm[k] * a[b][t-k][o].
__global__ __launch_bounds__(256)
void psp_conv(const double* __restrict__ a, double* __restrict__ u, int OS)
{
    __shared__ double ash[125 * 64];   // 62.5 KB
    __shared__ double srmE[68];        // srmE[i] = srm[i-2] for i-2 in [1,61], else 0

    const int tid = threadIdx.x;
    if (tid < 68) {
        const int k = tid - 2;
        double v = 0.0;
        if (k >= 1 && k <= 61) {
            double wv = (double)k / 8.0 * exp(1.0 - (double)k / 8.0);
            v = (double)(float)wv;     // fp32-rounded tap, widened
        }
        srmE[tid] = v;
    }
    const int b  = blockIdx.z;
    const int T0 = blockIdx.y * 64;
    const int og = blockIdx.x * 64;
    const double* ap = a + (size_t)b * TT * OS + og;
    for (int e = tid; e < 125 * 64; e += 256) {
        const int r = e >> 6, o = e & 63;
        const int t = T0 - 61 + r;
        ash[e] = (t >= 0) ? ap[(size_t)t * OS + o] : 0.0;
    }
    __syncthreads();

    const int o   = tid & 63;
    const int tb0 = (tid >> 6) * 16;
    for (int g = 0; g < 4; ++g) {
        const int tb = tb0 + g * 4;
        double u0 = 0, u1 = 0, u2 = 0, u3 = 0;
        double w1 = srmE[64], w2 = srmE[65], w3 = srmE[66];   // zero pads
        for (int d = 0; d < 64; d += 4) {
            const double av0 = ash[(tb + d + 0) * 64 + o];
            const double av1 = ash[(tb + d + 1) * 64 + o];
            const double av2 = ash[(tb + d + 2) * 64 + o];
            const double av3 = ash[(tb + d + 3) * 64 + o];
            const double n0 = srmE[63 - d], n1 = srmE[62 - d];
            const double n2 = srmE[61 - d], n3 = srmE[60 - d];
            u0 = fma(n0, av0, u0); u1 = fma(w1, av0, u1); u2 = fma(w2, av0, u2); u3 = fma(w3, av0, u3);
            u0 = fma(n1, av1, u0); u1 = fma(n0, av1, u1); u2 = fma(w1, av1, u2); u3 = fma(w2, av1, u3);
            u0 = fma(n2, av2, u0); u1 = fma(n1, av2, u1); u2 = fma(n0, av2, u2); u3 = fma(w1, av2, u3);
            u0 = fma(n3, av3, u0); u1 = fma(n2, av3, u1); u2 = fma(n1, av3, u2); u3 = fma(n0, av3, u3);
            w1 = n3; w2 = n2; w3 = n1;
        }
        double* uo = u + ((size_t)b * TT + T0 + tb) * OS + og + o;
        uo[0] = u0; uo[OS] = u1; uo[2 * (size_t)OS] = u2; uo[3 * (size_t)OS] = u3;
    }
}

// ========================== scan (transposed output) ========================
__global__ __launch_bounds__(256)
void scan_spikes(const double* __restrict__ u, uint32_t* __restrict__ bitsT_out,
                 int OS, int obase, int OW)
{
    __shared__ double   ref64[KLEN];
    __shared__ uint32_t blds[8][256];   // 8 KB ballot staging
    const int tid = threadIdx.x;
    if (tid < KLEN) {
        double v = (double)tid / 8.0 * exp(1.0 - (double)tid / 8.0);
        ref64[tid] = (double)(float)(-20.0 * v);
    }
    __syncthreads();

    const int b    = blockIdx.y;
    const int o    = blockIdx.x * 256 + tid;   // within slice
    const int lane = tid & 63;
    const int wv   = tid >> 6;
    const double* up = u + (size_t)b * TT * OS + o;

    uint64_t mask = 0;
    double cur0 = up[0], cur1 = up[OS], cur2 = up[2 * (size_t)OS], cur3 = up[3 * (size_t)OS];
    for (int t0 = 0; t0 < TT; t0 += 4) {
        double nx0 = 0, nx1 = 0, nx2 = 0, nx3 = 0;
        if (t0 + 4 < TT) {
            const double* pp = up + (size_t)(t0 + 4) * OS;
            nx0 = pp[0]; nx1 = pp[OS]; nx2 = pp[2 * (size_t)OS]; nx3 = pp[3 * (size_t)OS];
        }
        #pragma unroll
        for (int q = 0; q < 4; ++q) {
            const double uv = (q == 0) ? cur0 : (q == 1) ? cur1 : (q == 2) ? cur2 : cur3;
            uint64_t m = mask;
            double r0 = 0.0, r1 = 0.0;
            while (m) {
                int p = __builtin_ctzll(m); m &= m - 1;
                r0 += ref64[p + 1];
                if (m) { int pq = __builtin_ctzll(m); m &= m - 1; r1 += ref64[pq + 1]; }
            }
            const bool s = (uv + (r0 + r1)) >= THETA;
            const uint64_t bal = __ballot(s);
            if (lane == 0) {
                blds[wv * 2 + 0][t0 + q] = (uint32_t)bal;
                blds[wv * 2 + 1][t0 + q] = (uint32_t)(bal >> 32);
            }
            mask = ((mask << 1) | (s ? 1ull : 0ull)) & ((1ull << 61) - 1ull);
        }
        cur0 = nx0; cur1 = nx1; cur2 = nx2; cur3 = nx3;
    }
    __syncthreads();
    const int wordbase = (obase + blockIdx.x * 256) >> 5;
    for (int e = tid; e < 8 * 256; e += 256) {
        const int wl = e >> 8, t = e & 255;
        bitsT_out[((size_t)b * OW + wordbase + wl) * TT + t] = blds[wl][t];
    }
}

// ============================ epilogue (transposed) =========================
__global__ __launch_bounds__(256)
void bits_to_f32T(const uint32_t* __restrict__ bitsT, float* __restrict__ out, int OW)
{
    const int b  = blockIdx.y;
    const int o  = blockIdx.x * 4 + (threadIdx.x >> 6);
    const int tq = (threadIdx.x & 63) * 4;
    const uint32_t* bp  = bitsT + ((size_t)b * OW + (o >> 5)) * TT + tq;
    const uint32_t  bit = 1u << (o & 31);
    float4 v;
    v.x = (bp[0] & bit) ? 1.0f : 0.0f;
    v.y = (bp[1] & bit) ? 1.0f : 0.0f;
    v.z = (bp[2] & bit) ? 1.0f : 0.0f;
    v.w = (bp[3] & bit) ? 1.0f : 0.0f;
    *(float4*)(out + ((size_t)b * 512 + o) * TT + tq) = v;
}

// =================== fallback: round-2 fused path (old layouts) =============
__global__ __launch_bounds__(256)
void bitify_rowmajor(const float* __restrict__ x, uint32_t* __restrict__ bits)
{
    const int b  = blockIdx.x;
    const int ig = blockIdx.y;
    const int t  = threadIdx.x;
    const float*  xp = x    + ((size_t)b*1024 + ig*128)*TT + t;
    uint32_t*     bp = bits + ((size_t)b*TT + t)*32 + ig*4;
    for (int wi = 0; wi < 4; ++wi) {
        uint32_t wb = 0;
        #pragma unroll
        for (int j = 0; j < 32; ++j)
            wb |= (xp[(size_t)(wi*32 + j)*TT] >= 0.5f) ? (1u << j) : 0u;
        bp[wi] = wb;
    }
}

#define CHUNK  16
#define NCHUNK (TT/CHUNK)
#define RING   80
#define RPAD   65

template<int I>
__global__ __launch_bounds__(256)
void snn_layer_sparse(const uint32_t* __restrict__ bits_in,
                      const float*    __restrict__ w,
                      uint32_t*       __restrict__ bits_out,
                      int O)
{
    __shared__ double ring[RING][RPAD];
    __shared__ double wu[2080];
    __shared__ double srm64[KLEN];
    __shared__ double ref64[KLEN];

    float*  wsh = (float*)wu;
    double* ush = wu;

    const int tid  = threadIdx.x;
    const int lane = tid & 63;
    const int wvu  = __builtin_amdgcn_readfirstlane(tid >> 6);
    const int b    = blockIdx.y;
    const int o0   = blockIdx.x * 64;
    const int IW   = I / 32;

    if (tid < KLEN) {
        double v = (double)tid / 8.0 * exp(1.0 - (double)tid / 8.0);
        srm64[tid] = (double)(float)v;
        ref64[tid] = (double)(float)(-20.0 * v);
    }
    for (int e = tid; e < RING*RPAD; e += 256) ((double*)ring)[e] = 0.0;

    auto gemm_chunk = [&](int c) {
        const int t0 = c * CHUNK;
        double acc[CHUNK/4];
        #pragma unroll
        for (int j = 0; j < CHUNK/4; ++j) acc[j] = 0.0;
        for (int ic = 0; ic < I/64; ++ic) {
            __syncthreads();
            {
                const int obase = tid >> 4;
                const int il4   = (tid & 15) * 4;
                #pragma unroll
                for (int p4 = 0; p4 < 4; ++p4) {
                    const int oo = obase + p4*16;
                    const float4 wv4 = *(const float4*)(w + (size_t)(o0+oo)*I + ic*64 + il4);
                    wsh[(il4+0)*RPAD + oo] = wv4.x;
                    wsh[(il4+1)*RPAD + oo] = wv4.y;
                    wsh[(il4+2)*RPAD + oo] = wv4.z;
                    wsh[(il4+3)*RPAD + oo] = wv4.w;
                }
            }
            __syncthreads();
            #pragma unroll
            for (int j = 0; j < CHUNK/4; ++j) {
                const int t = t0 + wvu*(CHUNK/4) + j;
                const uint64_t raw =
                    *(const uint64_t*)(bits_in + ((size_t)b*TT + t)*IW + ic*2);
                const uint32_t mlo = __builtin_amdgcn_readfirstlane((uint32_t)raw);
                const uint32_t mhi = __builtin_amdgcn_readfirstlane((uint32_t)(raw >> 32));
                uint64_t m = ((uint64_t)mhi << 32) | mlo;
                double a0 = 0.0, a1 = 0.0, a2 = 0.0, a3 = 0.0;
                while (m) {
                    float f0 = 0.f, f1 = 0.f, f2 = 0.f, f3 = 0.f;
                    int p = __builtin_ctzll(m); m &= m - 1;
                    f0 = wsh[p*RPAD + lane];
                    if (m) { p = __builtin_ctzll(m); m &= m - 1; f1 = wsh[p*RPAD + lane]; }
                    if (m) { p = __builtin_ctzll(m); m &= m - 1; f2 = wsh[p*RPAD + lane]; }
                    if (m) { p = __builtin_ctzll(m); m &= m - 1; f3 = wsh[p*RPAD + lane]; }
                    a0 += (double)f0; a1 += (double)f1; a2 += (double)f2; a3 += (double)f3;
                }
                acc[j] += (a0 + a1) + (a2 + a3);
            }
        }
        #pragma unroll
        for (int j = 0; j < CHUNK/4; ++j) {
            const int t = t0 + wvu*(CHUNK/4) + j;
            ring[t % RING][lane] = acc[j];
        }
    };

    auto conv_chunk = [&](int c) {
        const int t0 = c * CHUNK;
        const int tl = tid & (CHUNK-1);
        const int os = tid >> 4;
        const int t  = t0 + tl;
        double u0 = 0, u1 = 0, u2 = 0, u3 = 0;
        for (int k = 1; k < KLEN; ++k) {
            const double sv  = srm64[k];
            const int    row = (t - k + RING) % RING;
            const double* ap = &ring[row][os*4];
            u0 = fma(sv, ap[0], u0);
            u1 = fma(sv, ap[1], u1);
            u2 = fma(sv, ap[2], u2);
            u3 = fma(sv, ap[3], u3);
        }
        double* upp = &ush[tl*RPAD + os*4];
        upp[0] = u0; upp[1] = u1; upp[2] = u2; upp[3] = u3;
    };

    uint64_t mask = 0;
    auto scan_chunk = [&](int c) {
        const int t0 = c * CHUNK;
        for (int tl = 0; tl < CHUNK; ++tl) {
            const double uv = ush[tl*RPAD + lane];
            uint64_t m = mask;
            double r0 = 0.0, r1 = 0.0;
            while (m) {
                int p = __builtin_ctzll(m); m &= m - 1;
                r0 += ref64[p + 1];
                if (m) { int q = __builtin_ctzll(m); m &= m - 1; r1 += ref64[q + 1]; }
            }
            const bool s = (uv + (r0 + r1)) >= THETA;
            const uint64_t bal = __ballot(s);
            if (lane == 0)
                *(uint64_t*)(bits_out + ((size_t)b*TT + (t0 + tl))*(O/32) + (o0 >> 5)) = bal;
            mask = ((mask << 1) | (s ? 1ull : 0ull)) & ((1ull << 61) - 1ull);
        }
    };

    gemm_chunk(0);
    for (int c = 0; c < NCHUNK; ++c) {
        __syncthreads();
        conv_chunk(c);
        __syncthreads();
        if (wvu == 0) scan_chunk(c);
        __syncthreads();
        if (c + 1 < NCHUNK) gemm_chunk(c + 1);
    }
}

__global__ __launch_bounds__(256)
void bits_to_f32_rowmajor(const uint32_t* __restrict__ bits, float* __restrict__ out, int O)
{
    const int b  = blockIdx.y;
    const int o  = blockIdx.x*4 + (threadIdx.x >> 6);
    const int tq = (threadIdx.x & 63) * 4;
    const uint32_t* bp  = bits + (size_t)b*TT*(O/32) + (o >> 5);
    const uint32_t  bit = 1u << (o & 31);
    float4 v;
    v.x = (bp[(size_t)(tq+0)*(O/32)] & bit) ? 1.0f : 0.0f;
    v.y = (bp[(size_t)(tq+1)*(O/32)] & bit) ? 1.0f : 0.0f;
    v.z = (bp[(size_t)(tq+2)*(O/32)] & bit) ? 1.0f : 0.0f;
    v.w = (bp[(size_t)(tq+3)*(O/32)] & bit) ? 1.0f : 0.0f;
    *(float4*)(out + ((size_t)b*O + o)*TT + tq) = v;
}

// ================================ launcher ==================================
extern "C" void kernel_launch(void* const* d_in, const int* in_sizes, int n_in,
                              void* d_out, int out_size, void* d_ws, size_t ws_size,
                              hipStream_t stream)
{
    const float* x  = (const float*)d_in[0];   // [32][1024][256]
    const float* w1 = (const float*)d_in[1];   // [2048][1024]
    const float* w2 = (const float*)d_in[2];   // [512][2048]
    float* out = (float*)d_out;                // [32][512][256]

    uint32_t* bits1 = (uint32_t*)d_ws;                       // 1 MB
    uint32_t* bitsH = bits1 + (size_t)32*256*32;             // 2 MB
    uint32_t* bits2 = bitsH + (size_t)32*256*64;             // 0.5 MB
    const size_t bitsBytes = (size_t)32*256*(32+64+16)*4;
    const size_t base = (bitsBytes + 255) & ~(size_t)255;

    // a+u need 2 * 32*256*8 = 131072 B per output; balanced power-of-two slice
    size_t avail = (ws_size > base) ? ws_size - base : 0;
    long long osCap = (long long)(avail / 131072);
    int osSlice = 0;
    if      (osCap >= 2048) osSlice = 2048;
    else if (osCap >= 1024) osSlice = 1024;
    else if (osCap >=  512) osSlice =  512;
    else if (osCap >=  256) osSlice =  256;

    if (osSlice >= 256) {
        double* aBuf = (double*)((char*)d_ws + base);
        double* uBuf = (double*)((char*)d_ws + base + (size_t)osSlice * 65536);

        bitifyT<<<dim3(32, 8), 256, 0, stream>>>(x, bits1);
        // ---- layer 1: 1024 -> 2048 ----
        for (int ob = 0; ob < 2048; ob += osSlice) {
            const int os = (2048 - ob < osSlice) ? (2048 - ob) : osSlice;
            gemm_sparse<1024, 32><<<dim3(os/64, 2, 32), 256, 0, stream>>>(
                bits1, w1 + (size_t)ob * 1024, aBuf, os);
            psp_conv<<<dim3(os/64, 4, 32), 256, 0, stream>>>(aBuf, uBuf, os);
            scan_spikes<<<dim3(os/256, 32), 256, 0, stream>>>(uBuf, bitsH, os, ob, 64);
        }
        // ---- layer 2: 2048 -> 512 ----
        for (int ob = 0; ob < 512; ob += osSlice) {
            const int os = (512 - ob < osSlice) ? (512 - ob) : osSlice;
            gemm_sparse<2048, 16><<<dim3(os/64, 4, 32), 256, 0, stream>>>(
                bitsH, w2 + (size_t)ob * 2048, aBuf, os);
            psp_conv<<<dim3(os/64, 4, 32), 256, 0, stream>>>(aBuf, uBuf, os);
            scan_spikes<<<dim3(os/256, 32), 256, 0, stream>>>(uBuf, bits2, os, ob, 16);
        }
        bits_to_f32T<<<dim3(512/4, 32), 256, 0, stream>>>(bits2, out, 16);
    } else {
        // fallback: round-2 fused path (row-major bit layouts)
        bitify_rowmajor<<<dim3(32, 8), 256, 0, stream>>>(x, bits1);
        snn_layer_sparse<1024><<<dim3(2048/64, 32), 256, 0, stream>>>(bits1, w1, bitsH, 2048);
        snn_layer_sparse<2048><<<dim3(512/64, 32), 256, 0, stream>>>(bitsH, w2, bits2, 512);
        bits_to_f32_rowmajor<<<dim3(512/4, 32), 256, 0, stream>>>(bits2, out, 512);
    }
}

// Round 7
// 1416.082 us; speedup vs baseline: 1.0673x; 1.0673x over previous
//
#include <hip/hip_runtime.h>
#include <math.h>
#include <stdint.h>

// SLAYER 2-layer SNN. Round 7: exact bf16-MFMA digit-plane GEMM.
//   bitifyT -> decompose(W->5 bf16 integer digit planes) ->
//   per layer: [MFMA plane-GEMM (exact) -> FIR conv -> scan] -> bits_to_f32T.
// Exactness: w ~= (sum_p d_p 256^p) * 2^-38 with d_p in [-128,127] (exact int,
// only |w|<2^-18 weights rounded at 2^-39). bf16 digits exact; spike 0/1 exact;
// fp32 MFMA accum holds only integers < 2^24 => exact; fp64 recombine exact.
// conv/scan/bitify/epilogue unchanged from R6 (absmax 0.0, rounds 1-6).

#define TT     256
#define KLEN   62
#define THETA  10.0

typedef __attribute__((ext_vector_type(8))) short short8;
typedef __attribute__((ext_vector_type(4))) float f32x4;

// ============================ bitify (transposed) ===========================
// x: [32][1024][256] f32 {0,1}; bitsT: [b][32 words][256 t]
__global__ __launch_bounds__(256)
void bitifyT(const float* __restrict__ x, uint32_t* __restrict__ bitsT)
{
    const int b  = blockIdx.x;
    const int ig = blockIdx.y;            // group of 128 inputs (4 words)
    const int t  = threadIdx.x;
    const float* xp = x     + ((size_t)b*1024 + ig*128)*TT + t;
    uint32_t*    bp = bitsT + ((size_t)b*32 + ig*4)*TT + t;
    for (int wi = 0; wi < 4; ++wi) {
        uint32_t wb = 0;
        #pragma unroll
        for (int j = 0; j < 32; ++j)
            wb |= (xp[(size_t)(wi*32 + j)*TT] >= 0.5f) ? (1u << j) : 0u;
        bp[(size_t)wi * TT] = wb;
    }
}

// ====================== weight -> digit-plane decompose =====================
// planes layout: [oblk][kstep][m'(80 = p*16+olocal)][40 u16 (32 k + 8 pad)]
// = exactly the padded LDS tile, so staging is a flat copy.
__global__ __launch_bounds__(256)
void decompose(const float* __restrict__ w, ushort* __restrict__ planes,
               int I, int total)
{
    const int f = blockIdx.x * 256 + threadIdx.x;
    if (f >= total) return;
    const int NS = I / 32;
    const int per_oblk = NS * 3200;
    int rem  = f;
    const int oblk = rem / per_oblk;  rem -= oblk * per_oblk;
    const int ks   = rem / 3200;      rem -= ks * 3200;
    const int mp   = rem / 40;
    const int kk   = rem - mp * 40;
    ushort h = 0;
    if (kk < 32) {
        const int p  = mp >> 4, mo = mp & 15;
        const float wv = w[(size_t)(oblk*16 + mo) * I + ks*32 + kk];
        long long v = llrint((double)wv * 274877906944.0);   // w * 2^38, exact int
        int d = 0;
        for (int q = 0; q <= p; ++q) {                       // balanced base-256 digits
            d = (int)((v + 128) & 255) - 128;
            v = (v - d) >> 8;
        }
        h = (ushort)(__float_as_uint((float)d) >> 16);       // exact bf16 of int digit
    }
    planes[f] = h;
}

// ====================== exact MFMA plane-GEMM ===============================
// a[b][t][o] (fp64) = sum_i w[o][i] * s[i][t], via 5 bf16 digit planes.
// block: 16 o x 256 t x one b; 4 waves each 80 M'(5 planes x 16 o) x 64 t.
// K-loop: 32 i per step, A/B tiles double-buffered in LDS (padded 80-B rows).
template<int I>
__global__ __launch_bounds__(256)
void gemm_planes(const uint32_t* __restrict__ bitsT,   // [B][I/32][TT]
                 const ushort*   __restrict__ planes,  // slice base
                 double*         __restrict__ a_out,   // [B][TT][OS]
                 int OS)
{
    constexpr int IW = I / 32;
    constexpr int NS = I / 32;
    __shared__ __align__(16) ushort ash[2][80 * 40];    // 12.8 KB
    __shared__ __align__(16) ushort bsh[2][256 * 40];   // 40.96 KB (epi overlay)

    const int tid  = threadIdx.x;
    const int lane = tid & 63;
    const int wvu  = tid >> 6;
    const int quad = lane >> 4;
    const int col  = lane & 15;
    const int b    = blockIdx.y;
    const int oblk = blockIdx.x;
    const int o0   = oblk * 16;

    const ushort* Apg = planes + (size_t)oblk * NS * 3200;

    f32x4 acc[5][4];
    #pragma unroll
    for (int p = 0; p < 5; ++p)
        #pragma unroll
        for (int nt = 0; nt < 4; ++nt)
            acc[p][nt] = (f32x4){0.f, 0.f, 0.f, 0.f};

    auto stageA = [&](int s) {
        const uint* src = (const uint*)(Apg + (size_t)s * 3200);
        uint*       dst = (uint*)ash[s & 1];
        #pragma unroll
        for (int e = 0; e < 7; ++e) {                 // 7*256 = 1792 >= 1600
            const int idx = tid + e * 256;
            if (idx < 1600) dst[idx] = src[idx];
        }
    };
    auto stageB = [&](int s) {
        const uint32_t w = bitsT[((size_t)b * IW + s) * 256 + tid];
        uint* row = (uint*)(bsh[s & 1] + tid * 40);
        #pragma unroll
        for (int j = 0; j < 16; ++j)
            row[j] = (((w >> (2*j))   & 1u) ? 0x3F80u     : 0u) |
                     (((w >> (2*j+1)) & 1u) ? 0x3F800000u : 0u);
    };
    auto compute = [&](int s) {
        const ushort* ap = ash[s & 1];
        const ushort* bp = bsh[s & 1];
        short8 af[5], bf[4];
        #pragma unroll
        for (int p = 0; p < 5; ++p)
            af[p] = *(const short8*)(const void*)(ap + (p*16 + col)*40 + quad*8);
        #pragma unroll
        for (int nt = 0; nt < 4; ++nt)
            bf[nt] = *(const short8*)(const void*)(bp + (wvu*64 + nt*16 + col)*40 + quad*8);
        #pragma unroll
        for (int p = 0; p < 5; ++p)
            #pragma unroll
            for (int nt = 0; nt < 4; ++nt)
                acc[p][nt] = __builtin_amdgcn_mfma_f32_16x16x32_bf16(
                                 af[p], bf[nt], acc[p][nt], 0, 0, 0);
    };

    stageA(0); stageB(0);
    __syncthreads();
    for (int s = 0; s < NS; ++s) {
        if (s + 1 < NS) { stageA(s + 1); stageB(s + 1); }
        compute(s);
        __syncthreads();
    }

    // ---- epilogue: fp64 recombine + LDS shuffle for coalesced stores ----
    double* epi = (double*)(void*)&bsh[0][0] + (size_t)wvu * 1088;  // 64 x 17
    const double inv = 1.0 / 274877906944.0;                        // 2^-38
    #pragma unroll
    for (int nt = 0; nt < 4; ++nt)
        #pragma unroll
        for (int r = 0; r < 4; ++r) {
            double v =            (double)acc[4][nt][r];
            v = v * 256.0 + (double)acc[3][nt][r];
            v = v * 256.0 + (double)acc[2][nt][r];
            v = v * 256.0 + (double)acc[1][nt][r];
            v = v * 256.0 + (double)acc[0][nt][r];
            epi[(nt*16 + col) * 17 + (quad*4 + r)] = v * inv;
        }
    __syncthreads();
    double* aout = a_out + ((size_t)b * 256 + wvu * 64) * OS + o0;
    #pragma unroll
    for (int k = 0; k < 16; ++k) {
        const int n = k*4 + quad;
        aout[(size_t)n * OS + col] = epi[n * 17 + col];
    }
}

// ========================== FIR conv (unchanged) ============================
__global__ __launch_bounds__(256)
void psp_conv(const double* __restrict__ a, double* __restrict__ u, int OS)
{
    __shared__ double ash[125 * 64];
    __shared__ double srmE[68];

    const int tid = threadIdx.x;
    if (tid < 68) {
        const int k = tid - 2;
        double v = 0.0;
        if (k >= 1 && k <= 61) {
            double wv = (double)k / 8.0 * exp(1.0 - (double)k / 8.0);
            v = (double)(float)wv;
        }
        srmE[tid] = v;
    }
    const int b  = blockIdx.z;
    const int T0 = blockIdx.y * 64;
    const int og = blockIdx.x * 64;
    const double* ap = a + (size_t)b * TT * OS + og;
    for (int e = tid; e < 125 * 64; e += 256) {
        const int r = e >> 6, o = e & 63;
        const int t = T0 - 61 + r;
        ash[e] = (t >= 0) ? ap[(size_t)t * OS + o] : 0.0;
    }
    __syncthreads();

    const int o   = tid & 63;
    const int tb0 = (tid >> 6) * 16;
    for (int g = 0; g < 4; ++g) {
        const int tb = tb0 + g * 4;
        double u0 = 0, u1 = 0, u2 = 0, u3 = 0;
        double w1 = srmE[64], w2 = srmE[65], w3 = srmE[66];
        for (int d = 0; d < 64; d += 4) {
            const double av0 = ash[(tb + d + 0) * 64 + o];
            const double av1 = ash[(tb + d + 1) * 64 + o];
            const double av2 = ash[(tb + d + 2) * 64 + o];
            const double av3 = ash[(tb + d + 3) * 64 + o];
            const double n0 = srmE[63 - d], n1 = srmE[62 - d];
            const double n2 = srmE[61 - d], n3 = srmE[60 - d];
            u0 = fma(n0, av0, u0); u1 = fma(w1, av0, u1); u2 = fma(w2, av0, u2); u3 = fma(w3, av0, u3);
            u0 = fma(n1, av1, u0); u1 = fma(n0, av1, u1); u2 = fma(w1, av1, u2); u3 = fma(w2, av1, u3);
            u0 = fma(n2, av2, u0); u1 = fma(n1, av2, u1); u2 = fma(n0, av2, u2); u3 = fma(w1, av2, u3);
            u0 = fma(n3, av3, u0); u1 = fma(n2, av3, u1); u2 = fma(n1, av3, u2); u3 = fma(n0, av3, u3);
            w1 = n3; w2 = n2; w3 = n1;
        }
        double* uo = u + ((size_t)b * TT + T0 + tb) * OS + og + o;
        uo[0] = u0; uo[OS] = u1; uo[2 * (size_t)OS] = u2; uo[3 * (size_t)OS] = u3;
    }
}

// ========================== scan (unchanged) ================================
__global__ __launch_bounds__(256)
void scan_spikes(const double* __restrict__ u, uint32_t* __restrict__ bitsT_out,
                 int OS, int obase, int OW)
{
    __shared__ double   ref64[KLEN];
    __shared__ uint32_t blds[8][256];
    const int tid = threadIdx.x;
    if (tid < KLEN) {
        double v = (double)tid / 8.0 * exp(1.0 - (double)tid / 8.0);
        ref64[tid] = (double)(float)(-20.0 * v);
    }
    __syncthreads();

    const int b    = blockIdx.y;
    const int o    = blockIdx.x * 256 + tid;
    const int lane = tid & 63;
    const int wv   = tid >> 6;
    const double* up = u + (size_t)b * TT * OS + o;

    uint64_t mask = 0;
    double cur0 = up[0], cur1 = up[OS], cur2 = up[2 * (size_t)OS], cur3 = up[3 * (size_t)OS];
    for (int t0 = 0; t0 < TT; t0 += 4) {
        double nx0 = 0, nx1 = 0, nx2 = 0, nx3 = 0;
        if (t0 + 4 < TT) {
            const double* pp = up + (size_t)(t0 + 4) * OS;
            nx0 = pp[0]; nx1 = pp[OS]; nx2 = pp[2 * (size_t)OS]; nx3 = pp[3 * (size_t)OS];
        }
        #pragma unroll
        for (int q = 0; q < 4; ++q) {
            const double uv = (q == 0) ? cur0 : (q == 1) ? cur1 : (q == 2) ? cur2 : cur3;
            uint64_t m = mask;
            double r0 = 0.0, r1 = 0.0;
            while (m) {
                int p = __builtin_ctzll(m); m &= m - 1;
                r0 += ref64[p + 1];
                if (m) { int pq = __builtin_ctzll(m); m &= m - 1; r1 += ref64[pq + 1]; }
            }
            const bool s = (uv + (r0 + r1)) >= THETA;
            const uint64_t bal = __ballot(s);
            if (lane == 0) {
                blds[wv * 2 + 0][t0 + q] = (uint32_t)bal;
                blds[wv * 2 + 1][t0 + q] = (uint32_t)(bal >> 32);
            }
            mask = ((mask << 1) | (s ? 1ull : 0ull)) & ((1ull << 61) - 1ull);
        }
        cur0 = nx0; cur1 = nx1; cur2 = nx2; cur3 = nx3;
    }
    __syncthreads();
    const int wordbase = (obase + blockIdx.x * 256) >> 5;
    for (int e = tid; e < 8 * 256; e += 256) {
        const int wl = e >> 8, t = e & 255;
        bitsT_out[((size_t)b * OW + wordbase + wl) * TT + t] = blds[wl][t];
    }
}

// ============================ epilogue (unchanged) ==========================
__global__ __launch_bounds__(256)
void bits_to_f32T(const uint32_t* __restrict__ bitsT, float* __restrict__ out, int OW)
{
    const int b  = blockIdx.y;
    const int o  = blockIdx.x * 4 + (threadIdx.x >> 6);
    const int tq = (threadIdx.x & 63) * 4;
    const uint32_t* bp  = bitsT + ((size_t)b * OW + (o >> 5)) * TT + tq;
    const uint32_t  bit = 1u << (o & 31);
    float4 v;
    v.x = (bp[0] & bit) ? 1.0f : 0.0f;
    v.y = (bp[1] & bit) ? 1.0f : 0.0f;
    v.z = (bp[2] & bit) ? 1.0f : 0.0f;
    v.w = (bp[3] & bit) ? 1.0f : 0.0f;
    *(float4*)(out + ((size_t)b * 512 + o) * TT + tq) = v;
}

// ================================ launcher ==================================
extern "C" void kernel_launch(void* const* d_in, const int* in_sizes, int n_in,
                              void* d_out, int out_size, void* d_ws, size_t ws_size,
                              hipStream_t stream)
{
    const float* x  = (const float*)d_in[0];   // [32][1024][256]
    const float* w1 = (const float*)d_in[1];   // [2048][1024]
    const float* w2 = (const float*)d_in[2];   // [512][2048]
    float* out = (float*)d_out;                // [32][512][256]

    // ---- workspace layout ----
    char* ws = (char*)d_ws;
    uint32_t* bits1 = (uint32_t*)ws;                         // 32*32*256*4  = 1 MB
    uint32_t* bitsH = bits1 + (size_t)32*32*256;             // 32*64*256*4  = 2 MB
    uint32_t* bits2 = bitsH + (size_t)32*64*256;             // 32*16*256*4  = 0.5 MB
    size_t off = ((size_t)32*(32+64+16)*256*4 + 255) & ~(size_t)255;
    ushort* P1 = (ushort*)(ws + off);                        // 128*32*3200*2 = 26.2 MB
    off += (size_t)128*32*3200*2;
    ushort* P2 = (ushort*)(ws + off);                        // 32*64*3200*2  = 13.1 MB
    off += (size_t)32*64*3200*2;
    off = (off + 255) & ~(size_t)255;

    // pick o-slice for fp64 a/u buffers
    int os = 512;
    if (ws_size < off + 2 * (size_t)512*32*256*8) os = 256;
    double* aBuf = (double*)(ws + off);
    double* uBuf = (double*)(ws + off + (size_t)os*32*256*8);

    bitifyT<<<dim3(32, 8), 256, 0, stream>>>(x, bits1);
    decompose<<<dim3((13107200 + 255)/256), 256, 0, stream>>>(w1, P1, 1024, 13107200);
    decompose<<<dim3((6553600  + 255)/256), 256, 0, stream>>>(w2, P2, 2048, 6553600);

    // ---- layer 1: 1024 -> 2048 ----
    for (int ob = 0; ob < 2048; ob += os) {
        gemm_planes<1024><<<dim3(os/16, 32), 256, 0, stream>>>(
            bits1, P1 + (size_t)(ob/16)*32*3200, aBuf, os);
        psp_conv<<<dim3(os/64, 4, 32), 256, 0, stream>>>(aBuf, uBuf, os);
        scan_spikes<<<dim3(os/256, 32), 256, 0, stream>>>(uBuf, bitsH, os, ob, 64);
    }
    // ---- layer 2: 2048 -> 512 ----
    for (int ob = 0; ob < 512; ob += os) {
        gemm_planes<2048><<<dim3(os/16, 32), 256, 0, stream>>>(
            bitsH, P2 + (size_t)(ob/16)*64*3200, aBuf, os);
        psp_conv<<<dim3(os/64, 4, 32), 256, 0, stream>>>(aBuf, uBuf, os);
        scan_spikes<<<dim3(os/256, 32), 256, 0, stream>>>(uBuf, bits2, os, ob, 16);
    }

    bits_to_f32T<<<dim3(512/4, 32), 256, 0, stream>>>(bits2, out, 16);
}

// Round 8
// 981.437 us; speedup vs baseline: 1.5400x; 1.4429x over previous
//
#include <hip/hip_runtime.h>
#include <math.h>
#include <stdint.h>

// SLAYER 2-layer SNN. Round 8: MFMA plane-GEMM with register-built B.
//   bitifyT -> decompose(W->5 bf16 integer digit planes) ->
//   per layer: [MFMA plane-GEMM (exact) -> FIR conv -> scan] -> bits_to_f32T.
// R7 diagnosis: gemm LDS-bound on B staging (8-way conflicted writes, 16.6%
// MfmaUtil). R8: B-fragments built in registers from spike bits (5 ops/dword,
// bit-identical packing), A-tile LDS dbuf only (12.8 KB, linear conflict-free
// staging), direct coalesced C stores (no epilogue LDS), waves cover 128 t.
// Exactness unchanged: integer digit planes, fp32 MFMA accum < 2^24, fp64
// recombine (absmax 0.0 in round 7). conv/scan/bitify unchanged (rounds 1-7).

#define TT     256
#define KLEN   62
#define THETA  10.0

typedef __attribute__((ext_vector_type(8))) short short8;
typedef __attribute__((ext_vector_type(4))) float f32x4;

// ============================ bitify (transposed) ===========================
// x: [32][1024][256] f32 {0,1}; bitsT: [b][32 words][256 t]
__global__ __launch_bounds__(256)
void bitifyT(const float* __restrict__ x, uint32_t* __restrict__ bitsT)
{
    const int b  = blockIdx.x;
    const int ig = blockIdx.y;            // group of 128 inputs (4 words)
    const int t  = threadIdx.x;
    const float* xp = x     + ((size_t)b*1024 + ig*128)*TT + t;
    uint32_t*    bp = bitsT + ((size_t)b*32 + ig*4)*TT + t;
    for (int wi = 0; wi < 4; ++wi) {
        uint32_t wb = 0;
        #pragma unroll
        for (int j = 0; j < 32; ++j)
            wb |= (xp[(size_t)(wi*32 + j)*TT] >= 0.5f) ? (1u << j) : 0u;
        bp[(size_t)wi * TT] = wb;
    }
}

// ====================== weight -> digit-plane decompose =====================
// planes layout: [oblk][kstep][m'(80 = p*16+olocal)][40 u16 (32 k + 8 pad)]
__global__ __launch_bounds__(256)
void decompose(const float* __restrict__ w, ushort* __restrict__ planes,
               int I, int total)
{
    const int f = blockIdx.x * 256 + threadIdx.x;
    if (f >= total) return;
    const int NS = I / 32;
    const int per_oblk = NS * 3200;
    int rem  = f;
    const int oblk = rem / per_oblk;  rem -= oblk * per_oblk;
    const int ks   = rem / 3200;      rem -= ks * 3200;
    const int mp   = rem / 40;
    const int kk   = rem - mp * 40;
    ushort h = 0;
    if (kk < 32) {
        const int p  = mp >> 4, mo = mp & 15;
        const float wv = w[(size_t)(oblk*16 + mo) * I + ks*32 + kk];
        long long v = llrint((double)wv * 274877906944.0);   // w * 2^38, exact int
        int d = 0;
        for (int q = 0; q <= p; ++q) {                       // balanced base-256 digits
            d = (int)((v + 128) & 255) - 128;
            v = (v - d) >> 8;
        }
        h = (ushort)(__float_as_uint((float)d) >> 16);       // exact bf16 of int digit
    }
    planes[f] = h;
}

// ====================== exact MFMA plane-GEMM ===============================
// a[b][t][o] (fp64) = sum_i w[o][i] * s[i][t], via 5 bf16 digit planes.
// block: 16 o x 2 batches x 256 t. wave w: b = 2*by+(w>>1), t-half (w&1)*128,
// covering 8 N-tiles of 16 t. A-tile (80 x 40 u16) LDS double-buffered;
// B-fragments built in registers from spike bits; C stored direct (coalesced).
template<int I>
__global__ __launch_bounds__(256)
void gemm_planes(const uint32_t* __restrict__ bitsT,   // [B][I/32][TT]
                 const ushort*   __restrict__ planes,  // slice base
                 double*         __restrict__ a_out,   // [B][TT][OS]
                 int OS)
{
    constexpr int IW = I / 32;
    constexpr int NS = I / 32;
    __shared__ __align__(16) ushort ash[2][3200];      // 12.8 KB total

    const int tid  = threadIdx.x;
    const int lane = tid & 63;
    const int wvu  = tid >> 6;
    const int quad = lane >> 4;
    const int col  = lane & 15;
    const int oblk = blockIdx.x;
    const int b    = blockIdx.y * 2 + (wvu >> 1);
    const int tw   = (wvu & 1) * 128;
    const int o0   = oblk * 16;
    const int sh   = quad * 8;                         // bit base for this quad

    const ushort*   Apg = planes + (size_t)oblk * NS * 3200;
    const uint32_t* bwp = bitsT  + (size_t)b * IW * 256 + tw + col;

    f32x4 acc[5][8];
    #pragma unroll
    for (int p = 0; p < 5; ++p)
        #pragma unroll
        for (int nt = 0; nt < 8; ++nt)
            acc[p][nt] = (f32x4){0.f, 0.f, 0.f, 0.f};

    uint4 st0, st1;
    auto ldglob = [&](int s) {                         // 400 uint4 per tile
        const uint4* src = (const uint4*)(Apg + (size_t)s * 3200);
        st0 = src[tid];
        if (tid < 144) st1 = src[256 + tid];
    };
    auto stw = [&](int s) {                            // linear -> conflict-free
        uint4* dst = (uint4*)ash[s & 1];
        dst[tid] = st0;
        if (tid < 144) dst[256 + tid] = st1;
    };

    ldglob(0); stw(0);
    __syncthreads();

    for (int s = 0; s < NS; ++s) {
        const bool more = (s + 1 < NS);
        if (more) ldglob(s + 1);

        uint32_t wsv[8];
        #pragma unroll
        for (int nt = 0; nt < 8; ++nt)
            wsv[nt] = bwp[(size_t)s * 256 + nt * 16];

        const ushort* ap = ash[s & 1];
        short8 af[5];
        #pragma unroll
        for (int p = 0; p < 5; ++p)
            af[p] = *(const short8*)(const void*)(ap + (p*16 + col)*40 + quad*8);

        #pragma unroll
        for (int nt = 0; nt < 8; ++nt) {
            const uint32_t wq = wsv[nt] >> sh;
            union { uint32_t u[4]; short8 v; } bf;
            #pragma unroll
            for (int j = 0; j < 4; ++j) {
                const uint32_t p2 = (wq >> (2*j)) & 3u;
                // bit even -> low ushort 0x3F80 (bf16 1.0), bit odd -> high ushort
                bf.u[j] = ((p2 & 1u) | ((p2 << 15) & 0x10000u)) * 0x3F80u;
            }
            #pragma unroll
            for (int p = 0; p < 5; ++p)
                acc[p][nt] = __builtin_amdgcn_mfma_f32_16x16x32_bf16(
                                 af[p], bf.v, acc[p][nt], 0, 0, 0);
        }

        if (more) stw(s + 1);
        __syncthreads();
    }

    // ---- epilogue: fp64 recombine, direct coalesced stores ----
    // lane(quad,col) reg r of acc[p][nt] = D[m=quad*4+r][n=col] -> o=o0+quad*4+r,
    // t = tw + nt*16 + col. 4 consecutive o per lane -> 32 B contiguous.
    const double inv = 1.0 / 274877906944.0;           // 2^-38
    #pragma unroll
    for (int nt = 0; nt < 8; ++nt) {
        double v[4];
        #pragma unroll
        for (int r = 0; r < 4; ++r) {
            double s =            (double)acc[4][nt][r];
            s = s * 256.0 + (double)acc[3][nt][r];
            s = s * 256.0 + (double)acc[2][nt][r];
            s = s * 256.0 + (double)acc[1][nt][r];
            s = s * 256.0 + (double)acc[0][nt][r];
            v[r] = s * inv;
        }
        double* dst = a_out + ((size_t)b * 256 + tw + nt*16 + col) * OS
                            + o0 + quad * 4;
        *(double2*)(void*)(dst + 0) = (double2){v[0], v[1]};
        *(double2*)(void*)(dst + 2) = (double2){v[2], v[3]};
    }
}

// ========================== FIR conv (unchanged) ============================
__global__ __launch_bounds__(256)
void psp_conv(const double* __restrict__ a, double* __restrict__ u, int OS)
{
    __shared__ double ash[125 * 64];
    __shared__ double srmE[68];

    const int tid = threadIdx.x;
    if (tid < 68) {
        const int k = tid - 2;
        double v = 0.0;
        if (k >= 1 && k <= 61) {
            double wv = (double)k / 8.0 * exp(1.0 - (double)k / 8.0);
            v = (double)(float)wv;
        }
        srmE[tid] = v;
    }
    const int b  = blockIdx.z;
    const int T0 = blockIdx.y * 64;
    const int og = blockIdx.x * 64;
    const double* ap = a + (size_t)b * TT * OS + og;
    for (int e = tid; e < 125 * 64; e += 256) {
        const int r = e >> 6, o = e & 63;
        const int t = T0 - 61 + r;
        ash[e] = (t >= 0) ? ap[(size_t)t * OS + o] : 0.0;
    }
    __syncthreads();

    const int o   = tid & 63;
    const int tb0 = (tid >> 6) * 16;
    for (int g = 0; g < 4; ++g) {
        const int tb = tb0 + g * 4;
        double u0 = 0, u1 = 0, u2 = 0, u3 = 0;
        double w1 = srmE[64], w2 = srmE[65], w3 = srmE[66];
        for (int d = 0; d < 64; d += 4) {
            const double av0 = ash[(tb + d + 0) * 64 + o];
            const double av1 = ash[(tb + d + 1) * 64 + o];
            const double av2 = ash[(tb + d + 2) * 64 + o];
            const double av3 = ash[(tb + d + 3) * 64 + o];
            const double n0 = srmE[63 - d], n1 = srmE[62 - d];
            const double n2 = srmE[61 - d], n3 = srmE[60 - d];
            u0 = fma(n0, av0, u0); u1 = fma(w1, av0, u1); u2 = fma(w2, av0, u2); u3 = fma(w3, av0, u3);
            u0 = fma(n1, av1, u0); u1 = fma(n0, av1, u1); u2 = fma(w1, av1, u2); u3 = fma(w2, av1, u3);
            u0 = fma(n2, av2, u0); u1 = fma(n1, av2, u1); u2 = fma(n0, av2, u2); u3 = fma(w1, av2, u3);
            u0 = fma(n3, av3, u0); u1 = fma(n2, av3, u1); u2 = fma(n1, av3, u2); u3 = fma(n0, av3, u3);
            w1 = n3; w2 = n2; w3 = n1;
        }
        double* uo = u + ((size_t)b * TT + T0 + tb) * OS + og + o;
        uo[0] = u0; uo[OS] = u1; uo[2 * (size_t)OS] = u2; uo[3 * (size_t)OS] = u3;
    }
}

// ========================== scan (unchanged) ================================
__global__ __launch_bounds__(256)
void scan_spikes(const double* __restrict__ u, uint32_t* __restrict__ bitsT_out,
                 int OS, int obase, int OW)
{
    __shared__ double   ref64[KLEN];
    __shared__ uint32_t blds[8][256];
    const int tid = threadIdx.x;
    if (tid < KLEN) {
        double v = (double)tid / 8.0 * exp(1.0 - (double)tid / 8.0);
        ref64[tid] = (double)(float)(-20.0 * v);
    }
    __syncthreads();

    const int b    = blockIdx.y;
    const int o    = blockIdx.x * 256 + tid;
    const int lane = tid & 63;
    const int wv   = tid >> 6;
    const double* up = u + (size_t)b * TT * OS + o;

    uint64_t mask = 0;
    double cur0 = up[0], cur1 = up[OS], cur2 = up[2 * (size_t)OS], cur3 = up[3 * (size_t)OS];
    for (int t0 = 0; t0 < TT; t0 += 4) {
        double nx0 = 0, nx1 = 0, nx2 = 0, nx3 = 0;
        if (t0 + 4 < TT) {
            const double* pp = up + (size_t)(t0 + 4) * OS;
            nx0 = pp[0]; nx1 = pp[OS]; nx2 = pp[2 * (size_t)OS]; nx3 = pp[3 * (size_t)OS];
        }
        #pragma unroll
        for (int q = 0; q < 4; ++q) {
            const double uv = (q == 0) ? cur0 : (q == 1) ? cur1 : (q == 2) ? cur2 : cur3;
            uint64_t m = mask;
            double r0 = 0.0, r1 = 0.0;
            while (m) {
                int p = __builtin_ctzll(m); m &= m - 1;
                r0 += ref64[p + 1];
                if (m) { int pq = __builtin_ctzll(m); m &= m - 1; r1 += ref64[pq + 1]; }
            }
            const bool s = (uv + (r0 + r1)) >= THETA;
            const uint64_t bal = __ballot(s);
            if (lane == 0) {
                blds[wv * 2 + 0][t0 + q] = (uint32_t)bal;
                blds[wv * 2 + 1][t0 + q] = (uint32_t)(bal >> 32);
            }
            mask = ((mask << 1) | (s ? 1ull : 0ull)) & ((1ull << 61) - 1ull);
        }
        cur0 = nx0; cur1 = nx1; cur2 = nx2; cur3 = nx3;
    }
    __syncthreads();
    const int wordbase = (obase + blockIdx.x * 256) >> 5;
    for (int e = tid; e < 8 * 256; e += 256) {
        const int wl = e >> 8, t = e & 255;
        bitsT_out[((size_t)b * OW + wordbase + wl) * TT + t] = blds[wl][t];
    }
}

// ============================ epilogue (unchanged) ==========================
__global__ __launch_bounds__(256)
void bits_to_f32T(const uint32_t* __restrict__ bitsT, float* __restrict__ out, int OW)
{
    const int b  = blockIdx.y;
    const int o  = blockIdx.x * 4 + (threadIdx.x >> 6);
    const int tq = (threadIdx.x & 63) * 4;
    const uint32_t* bp  = bitsT + ((size_t)b * OW + (o >> 5)) * TT + tq;
    const uint32_t  bit = 1u << (o & 31);
    float4 v;
    v.x = (bp[0] & bit) ? 1.0f : 0.0f;
    v.y = (bp[1] & bit) ? 1.0f : 0.0f;
    v.z = (bp[2] & bit) ? 1.0f : 0.0f;
    v.w = (bp[3] & bit) ? 1.0f : 0.0f;
    *(float4*)(out + ((size_t)b * 512 + o) * TT + tq) = v;
}

// ================================ launcher ==================================
extern "C" void kernel_launch(void* const* d_in, const int* in_sizes, int n_in,
                              void* d_out, int out_size, void* d_ws, size_t ws_size,
                              hipStream_t stream)
{
    const float* x  = (const float*)d_in[0];   // [32][1024][256]
    const float* w1 = (const float*)d_in[1];   // [2048][1024]
    const float* w2 = (const float*)d_in[2];   // [512][2048]
    float* out = (float*)d_out;                // [32][512][256]

    // ---- workspace layout ----
    char* ws = (char*)d_ws;
    uint32_t* bits1 = (uint32_t*)ws;                         // 1 MB
    uint32_t* bitsH = bits1 + (size_t)32*32*256;             // 2 MB
    uint32_t* bits2 = bitsH + (size_t)32*64*256;             // 0.5 MB
    size_t off = ((size_t)32*(32+64+16)*256*4 + 255) & ~(size_t)255;
    ushort* P1 = (ushort*)(ws + off);                        // 26.2 MB
    off += (size_t)128*32*3200*2;
    ushort* P2 = (ushort*)(ws + off);                        // 13.1 MB
    off += (size_t)32*64*3200*2;
    off = (off + 255) & ~(size_t)255;

    // o-slice for fp64 a/u buffers: prefer 1024 (177 MB total), else 512, 256
    const size_t perO = (size_t)32 * 256 * 8;                // 65536 B per output
    int os = 256;
    if (ws_size >= off + 2 * (size_t)1024 * perO) os = 1024;
    else if (ws_size >= off + 2 * (size_t)512 * perO) os = 512;
    double* aBuf = (double*)(ws + off);
    double* uBuf = (double*)(ws + off + (size_t)os * perO);

    bitifyT<<<dim3(32, 8), 256, 0, stream>>>(x, bits1);
    decompose<<<dim3((13107200 + 255)/256), 256, 0, stream>>>(w1, P1, 1024, 13107200);
    decompose<<<dim3((6553600  + 255)/256), 256, 0, stream>>>(w2, P2, 2048, 6553600);

    // ---- layer 1: 1024 -> 2048 ----
    for (int ob = 0; ob < 2048; ob += os) {
        const int o_s = (2048 - ob < os) ? (2048 - ob) : os;
        gemm_planes<1024><<<dim3(o_s/16, 16), 256, 0, stream>>>(
            bits1, P1 + (size_t)(ob/16)*32*3200, aBuf, o_s);
        psp_conv<<<dim3(o_s/64, 4, 32), 256, 0, stream>>>(aBuf, uBuf, o_s);
        scan_spikes<<<dim3(o_s/256, 32), 256, 0, stream>>>(uBuf, bitsH, o_s, ob, 64);
    }
    // ---- layer 2: 2048 -> 512 ----
    for (int ob = 0; ob < 512; ob += os) {
        const int o_s = (512 - ob < os) ? (512 - ob) : os;
        gemm_planes<2048><<<dim3(o_s/16, 16), 256, 0, stream>>>(
            bitsH, P2 + (size_t)(ob/16)*64*3200, aBuf, o_s);
        psp_conv<<<dim3(o_s/64, 4, 32), 256, 0, stream>>>(aBuf, uBuf, o_s);
        scan_spikes<<<dim3(o_s/256, 32), 256, 0, stream>>>(uBuf, bits2, o_s, ob, 16);
    }

    bits_to_f32T<<<dim3(512/4, 32), 256, 0, stream>>>(bits2, out, 16);
}